// Round 1
// baseline (464.420 us; speedup 1.0000x reference)
//
#include <hip/hip_runtime.h>

// Problem constants
#define T_LEN 8192
#define DMODEL 1536
#define NH 16
#define NKV 4
#define HD 96
#define KVDIM (NKV * HD)   // 384
#define W2 256             // WINDOW/2
#define NFREQ 48           // HD/2
#define NGB 32             // global-attention split-k blocks per head
#define NPROJ 3072         // total projection output columns (q + k + v + kg + vg)

static constexpr float SCALE = 0.10206207261596577f; // 1/sqrt(96)

typedef float f32x4 __attribute__((ext_vector_type(4)));
typedef short short8 __attribute__((ext_vector_type(8)));
typedef unsigned short ushort;

__device__ __forceinline__ ushort f2bf(float f) {
  unsigned int x = __float_as_uint(f);
  return (ushort)((x + 0x7FFFu + ((x >> 16) & 1u)) >> 16);
}
__device__ __forceinline__ float bf2f(ushort u) {
  return __uint_as_float((unsigned int)u << 16);
}
__device__ __forceinline__ void load_lds16(const void* g, void* l) {
  __builtin_amdgcn_global_load_lds(
      (const __attribute__((address_space(1))) void*)g,
      (__attribute__((address_space(3))) void*)l, 16, 0, 0);
}

// ---------------------------------------------------------------------------
// Elementwise fp32 -> bf16
// ---------------------------------------------------------------------------
__global__ __launch_bounds__(256) void convert_bf16(
    const float* __restrict__ in, ushort* __restrict__ out, int n4) {
  const int i = blockIdx.x * 256 + threadIdx.x;
  if (i >= n4) return;
  const f32x4 v = *(const f32x4*)&in[i * 4];
  ushort o[4] = {f2bf(v[0]), f2bf(v[1]), f2bf(v[2]), f2bf(v[3])};
  *(unsigned long long*)&out[i * 4] =
      (unsigned long long)o[0] | ((unsigned long long)o[1] << 16) |
      ((unsigned long long)o[2] << 32) | ((unsigned long long)o[3] << 48);
}

// ---------------------------------------------------------------------------
// W[K][N] fp32 -> Wt[N][K] bf16 (single)
// ---------------------------------------------------------------------------
__global__ __launch_bounds__(256) void transpose_bf16(
    const float* __restrict__ W, ushort* __restrict__ Wt, int K, int N) {
  __shared__ ushort tile[32][33];
  const int tx = threadIdx.x & 31;
  const int ty = threadIdx.x >> 5;
  const int n0 = blockIdx.x * 32;
  const int k0 = blockIdx.y * 32;
#pragma unroll
  for (int i = 0; i < 32; i += 8)
    tile[tx][ty + i] = f2bf(W[(size_t)(k0 + ty + i) * N + n0 + tx]);
  __syncthreads();
#pragma unroll
  for (int i = 0; i < 32; i += 8)
    Wt[(size_t)(n0 + ty + i) * K + k0 + tx] = tile[ty + i][tx];
}

// Batched version for the 4 KV weights (z selects source).
__global__ __launch_bounds__(256) void transpose_bf16_kv4(
    const float* __restrict__ Wk, const float* __restrict__ Wv,
    const float* __restrict__ Wkg, const float* __restrict__ Wvg,
    ushort* __restrict__ Wt) {
  const int z = blockIdx.z;
  const float* W = (z == 0) ? Wk : (z == 1) ? Wv : (z == 2) ? Wkg : Wvg;
  ushort* dst = Wt + (size_t)z * KVDIM * DMODEL;
  __shared__ ushort tile[32][33];
  const int tx = threadIdx.x & 31;
  const int ty = threadIdx.x >> 5;
  const int n0 = blockIdx.x * 32;
  const int k0 = blockIdx.y * 32;
#pragma unroll
  for (int i = 0; i < 32; i += 8)
    tile[tx][ty + i] = f2bf(W[(size_t)(k0 + ty + i) * KVDIM + n0 + tx]);
  __syncthreads();
#pragma unroll
  for (int i = 0; i < 32; i += 8)
    dst[(size_t)(n0 + ty + i) * DMODEL + k0 + tx] = tile[ty + i][tx];
}

// ---------------------------------------------------------------------------
// bf16 [T][KVDIM] -> bf16 [KVDIM][T] (V pre-transpose for local attn)
// ---------------------------------------------------------------------------
__global__ __launch_bounds__(256) void transpose_u16(
    const ushort* __restrict__ in, ushort* __restrict__ out) {
  __shared__ ushort tile[32][33];
  const int tx = threadIdx.x & 31;
  const int ty = threadIdx.x >> 5;
  const int c0 = blockIdx.x * 32;   // dim
  const int r0 = blockIdx.y * 32;   // t
#pragma unroll
  for (int i = 0; i < 32; i += 8)
    tile[ty + i][tx] = in[(size_t)(r0 + ty + i) * KVDIM + c0 + tx];
  __syncthreads();
#pragma unroll
  for (int i = 0; i < 32; i += 8)
    out[(size_t)(c0 + ty + i) * T_LEN + r0 + tx] = tile[tx][ty + i];
}

// ---------------------------------------------------------------------------
// 256x256 deep-pipelined bf16 GEMM core (K = 1536 = 48 tiles of BK=32).
// 8 waves (2M x 4N), 4-deep LDS ring buffer (4 x 32KB = 128KB), counted
// vmcnt (T3+T4), XOR-swizzled LDS reads (T2), setprio around MFMA (T5).
//
// LDS tile layout: [256 rows][32 bf16] = 64B rows; the 16B chunk index is
// XOR-swizzled with (row>>1)&3, applied identically on the pre-swizzled
// GLOBAL source (global_load_lds dest stays linear) and on the ds_read
// address, so fragment reads (16 lanes, 64B row stride) hit 8 distinct
// bank positions = free 2-way.
//
// Pipeline invariant: at iteration t's s_waitcnt, per-thread outstanding
// loads are tiles {t, t+1, t+2} = 12; vmcnt(8) confirms tile t (FIFO).
// Staging of tile t+3 overwrites buf[(t-1)&3], legal because all waves
// passed the barrier having finished tile t-1's reads.
// ---------------------------------------------------------------------------
#define WAITV(N) asm volatile("s_waitcnt vmcnt(" #N ")" ::: "memory")

#define STAGE(buf)                                                            \
  { char* db_ = lds + (buf) * 32768 + w * 1024;                               \
    load_lds16(sA0, db_);                                                     \
    load_lds16(sA1, db_ + 8192);                                              \
    load_lds16(sB0, db_ + 16384);                                             \
    load_lds16(sB1, db_ + 24576);                                             \
    sA0 += 32; sA1 += 32; sB0 += 32; sB1 += 32; }

#define TILE(t, VM, DOSTAGE)                                                  \
  { WAITV(VM);                                                                \
    __builtin_amdgcn_s_barrier();                                             \
    __builtin_amdgcn_sched_barrier(0);                                        \
    if (DOSTAGE) STAGE(((t) + 3) & 3)                                         \
    const char* Ab_ = lds + ((t) & 3) * 32768;                                \
    const char* Bb_ = Ab_ + 16384;                                            \
    short8 af_[8], bf_[4];                                                    \
    _Pragma("unroll") for (int mf = 0; mf < 8; ++mf)                          \
        af_[mf] = *(const short8*)(Ab_ + aoff + mf * 1024);                   \
    _Pragma("unroll") for (int nf = 0; nf < 4; ++nf)                          \
        bf_[nf] = *(const short8*)(Bb_ + boff + nf * 1024);                   \
    __builtin_amdgcn_s_setprio(1);                                            \
    _Pragma("unroll") for (int mf = 0; mf < 8; ++mf)                          \
        _Pragma("unroll") for (int nf = 0; nf < 4; ++nf)                      \
            acc[mf][nf] = __builtin_amdgcn_mfma_f32_16x16x32_bf16(            \
                af_[mf], bf_[nf], acc[mf][nf], 0, 0, 0);                      \
    __builtin_amdgcn_s_setprio(0);                                            \
  }

#define GEMM256_PRE(APTR, BPTR)                                               \
  __shared__ __align__(16) char lds[131072];                                  \
  const int tid = threadIdx.x;                                                \
  const int w = tid >> 6;                                                     \
  const int lane = tid & 63;                                                  \
  const int lo = lane & 15;                                                   \
  const int quad = lane >> 4;                                                 \
  const int wm = w >> 2;                                                      \
  const int wn = w & 3;                                                       \
  const int m0 = blockIdx.y * 256;                                            \
  const int n0 = blockIdx.x * 256;                                            \
  /* fragment-read swizzle: chunk ^= (row>>1)&3; row>>1&3 == (lo>>1)&3 */     \
  const int swz = (quad ^ ((lo >> 1) & 3)) << 4;                              \
  const int aoff = (wm * 128 + lo) * 64 + swz;                                \
  const int boff = (wn * 64 + lo) * 64 + swz;                                 \
  /* staging: idx in [0,1024) -> row = idx>>2, lds-chunk = idx&3; source */   \
  /* element chunk = ldschunk ^ ((row>>1)&3) (involution)               */    \
  const int rA0 = tid >> 2, cp0 = tid & 3;                                    \
  const int rA1 = 128 + rA0;                                                  \
  const int lc0 = cp0 ^ ((rA0 >> 1) & 3);                                     \
  const int lc1 = cp0 ^ ((rA1 >> 1) & 3);                                     \
  const ushort* sA0 = (APTR) + (size_t)(m0 + rA0) * 1536 + lc0 * 8;           \
  const ushort* sA1 = (APTR) + (size_t)(m0 + rA1) * 1536 + lc1 * 8;           \
  const ushort* sB0 = (BPTR) + (size_t)(n0 + rA0) * 1536 + lc0 * 8;           \
  const ushort* sB1 = (BPTR) + (size_t)(n0 + rA1) * 1536 + lc1 * 8;           \
  f32x4 acc[8][4];                                                            \
  _Pragma("unroll") for (int i = 0; i < 8; ++i)                               \
      _Pragma("unroll") for (int j = 0; j < 4; ++j)                           \
          acc[i][j] = {0.f, 0.f, 0.f, 0.f};                                   \
  STAGE(0) STAGE(1) STAGE(2)

#define GEMM256_LOOP()                                                        \
  _Pragma("unroll 1") for (int t = 0; t < 45; ++t) { TILE(t, 8, 1) }          \
  TILE(45, 8, 0) TILE(46, 4, 0) TILE(47, 0, 0)

// ---------------------------------------------------------------------------
// Unified projection GEMM: A[8192][1536] @ Wall[3072][1536]^T, 256^2 tiles.
// Column sections: [0,1536) q (rope, bf16) | [1536,1920) k (rope, bf16) |
// [1920,2304) v (bf16) | [2304,2688) kg (rope, f32) | [2688,3072) vg (f32).
// Sections are resolved PER COLUMN (256-wide blocks straddle boundaries).
// ---------------------------------------------------------------------------
__global__ __launch_bounds__(512) void gemm_proj256(
    const ushort* __restrict__ A, const ushort* __restrict__ Wall,
    ushort* __restrict__ q_bf, ushort* __restrict__ k_bf,
    ushort* __restrict__ v_bf, float* __restrict__ kg,
    float* __restrict__ vg, const float* __restrict__ cosf,
    const float* __restrict__ sinf, const int* __restrict__ pid) {
  GEMM256_PRE(A, Wall)
  GEMM256_LOOP()

  // ---- epilogue: fused RoPE + dtype routing ----
  __syncthreads();  // all LDS reads of the K-loop done; reuse lds
  const int xb = blockIdx.x;
  const bool blkRope = (xb <= 7) || (xb == 9) || (xb == 10);
  int* PidS = (int*)lds;                       // [256]
  unsigned int* CoefS = (unsigned int*)(lds + 1024);  // [256][48] cos|sin bf16
  if (blkRope) {
    if (tid < 256) PidS[tid] = pid[m0 + tid];
    __syncthreads();
#pragma unroll
    for (int j = 0; j < 24; ++j) {
      const int idx = j * 512 + tid;          // 0..12287
      const int rr = idx / 48;
      const int ff = idx - rr * 48;
      const int pos = PidS[rr];
      CoefS[idx] = (unsigned int)f2bf(cosf[(size_t)pos * NFREQ + ff]) |
                   ((unsigned int)f2bf(sinf[(size_t)pos * NFREQ + ff]) << 16);
    }
    __syncthreads();
  }

#pragma unroll
  for (int nf = 0; nf < 4; ++nf) {
    const int cc = n0 + wn * 64 + nf * 16 + lo;
    int sec, cbase;
    if (cc < 1536)      { sec = 0; cbase = 0; }
    else if (cc < 1920) { sec = 1; cbase = 1536; }
    else if (cc < 2304) { sec = 2; cbase = 1920; }
    else if (cc < 2688) { sec = 3; cbase = 2304; }
    else                { sec = 4; cbase = 2688; }
    const int col = cc - cbase;
    const int d = col % HD;
    const int fi = d >> 1;
    const bool doRope = (sec == 0) || (sec == 1) || (sec == 3);
#pragma unroll
    for (int mf = 0; mf < 8; ++mf) {
      const int lr0 = wm * 128 + mf * 16 + quad * 4;
#pragma unroll
      for (int r = 0; r < 4; ++r) {
        const int lr = lr0 + r;
        float v = acc[mf][nf][r];
        const float pe = __shfl_xor(v, 1);   // partner column (col^1)
        if (doRope) {
          const unsigned int pk = CoefS[lr * 48 + fi];
          const float co = bf2f((ushort)(pk & 0xFFFF));
          const float si = bf2f((ushort)(pk >> 16));
          v = (d & 1) ? fmaf(pe, si, v * co) : fmaf(v, co, -pe * si);
        }
        const int trow = m0 + lr;
        if (sec == 0)      q_bf[(size_t)trow * DMODEL + col] = f2bf(v);
        else if (sec == 1) k_bf[(size_t)trow * KVDIM + col] = f2bf(v);
        else if (sec == 2) v_bf[(size_t)trow * KVDIM + col] = f2bf(v);
        else if (sec == 3) kg[(size_t)trow * KVDIM + col] = v;
        else               vg[(size_t)trow * KVDIM + col] = v;
      }
    }
  }
}

// ---------------------------------------------------------------------------
// Output projection GEMM: attn[8192][1536] @ Wo_t[1536][1536]^T -> f32
// ---------------------------------------------------------------------------
__global__ __launch_bounds__(512) void gemm_out256(
    const ushort* __restrict__ A, const ushort* __restrict__ Bt,
    float* __restrict__ C) {
  GEMM256_PRE(A, Bt)
  GEMM256_LOOP()
#pragma unroll
  for (int mf = 0; mf < 8; ++mf) {
    const int r0 = m0 + wm * 128 + mf * 16 + quad * 4;
#pragma unroll
    for (int nf = 0; nf < 4; ++nf) {
      const int cc = n0 + wn * 64 + nf * 16 + lo;
#pragma unroll
      for (int r = 0; r < 4; ++r)
        C[(size_t)(r0 + r) * DMODEL + cc] = acc[mf][nf][r];
    }
  }
}

// ---------------------------------------------------------------------------
// qg row 0: zero + split-k atomics
// ---------------------------------------------------------------------------
__global__ void qg0_zero(float* __restrict__ qg0) {
  qg0[blockIdx.x * 256 + threadIdx.x] = 0.f;
}
__global__ __launch_bounds__(256) void qg0_split(
    const float* __restrict__ x, const float* __restrict__ W,
    float* __restrict__ qg0) {
  const int j = blockIdx.x * 256 + threadIdx.x;
  const int k0 = blockIdx.y * 128;
  float acc = 0.f;
#pragma unroll 8
  for (int k = k0; k < k0 + 128; ++k)
    acc = fmaf(x[k], W[(size_t)k * DMODEL + j], acc);
  atomicAdd(&qg0[j], acc);
}

// ---------------------------------------------------------------------------
// Local attention v4: MFMA bf16 flash tiles; V staged from pre-transposed
// Vt_g[KVDIM][T] via global_load_lds.
// ---------------------------------------------------------------------------
__global__ __launch_bounds__(256) void local_attn_v4(
    const ushort* __restrict__ qbf, const ushort* __restrict__ kbf,
    const ushort* __restrict__ vtg, const float* __restrict__ kg,
    const float* __restrict__ vg, ushort* __restrict__ obf) {
  __shared__ ushort Qb[3 * 64 * 32];
  __shared__ ushort Kb[3 * 64 * 32];
  __shared__ ushort Vt[2 * 96 * 32];   // panel kp: [96 dims][32 keys]
  __shared__ ushort Pb[4][2 * 16 * 32];
  __shared__ float Kg0[HD];
  __shared__ float Vg0[HD];

  const int t0 = blockIdx.x * 64;
  const int h  = blockIdx.y;
  const int kh = h >> 2;
  const int tid = threadIdx.x;
  const int w    = tid >> 6;
  const int lane = tid & 63;
  const int lo   = lane & 15;
  const int quad = lane >> 4;

  {
    const int rem = w * 64 + lane;
    const int row = rem >> 2;
    const int sub = (rem & 3) * 8;
#pragma unroll
    for (int j = 0; j < 3; ++j) {
      load_lds16(qbf + (size_t)(t0 + row) * DMODEL + h * HD + j * 32 + sub,
                 (char*)Qb + (j * 256 + w * 64) * 16);
    }
  }
  if (tid < HD) {
    Kg0[tid] = kg[kh * HD + tid];   // row 0 (rope at pos 0 = identity)
    Vg0[tid] = vg[kh * HD + tid];
  }

  f32x4 O[6];
#pragma unroll
  for (int i = 0; i < 6; ++i) O[i] = {0.f, 0.f, 0.f, 0.f};
  float m_run[4], l_run[4];
#pragma unroll
  for (int r = 0; r < 4; ++r) { m_run[r] = -1e30f; l_run[r] = 0.f; }

  __syncthreads();

  for (int ti = 0; ti < 5; ++ti) {
    const int kb = t0 - W2 + ti * 64;
    if (kb < 0) continue;

    {
      const int rem = w * 64 + lane;
      const int row = rem >> 2;
      const int sub = (rem & 3) * 8;
#pragma unroll
      for (int j = 0; j < 3; ++j) {
        load_lds16(kbf + (size_t)(kb + row) * KVDIM + kh * HD + j * 32 + sub,
                   (char*)Kb + (j * 256 + w * 64) * 16);
      }
#pragma unroll
      for (int j = 0; j < 3; ++j) {
        const int cc = j * 256 + w * 64 + lane;
        const int half = cc / 384;
        const int rm2 = cc - half * 384;
        const int dd = rm2 >> 2;
        const int sb = (rm2 & 3) * 8;
        load_lds16(vtg + (size_t)(kh * HD + dd) * T_LEN + kb + half * 32 + sb,
                   (char*)Vt + (j * 256 + w * 64) * 16);
      }
    }
    __syncthreads();

    short8 af[3];
#pragma unroll
    for (int p = 0; p < 3; ++p)
      af[p] = *(const short8*)&Qb[p * 2048 + (w * 16 + lo) * 32 + quad * 8];
    f32x4 s4[4];
#pragma unroll
    for (int nt = 0; nt < 4; ++nt) s4[nt] = {0.f, 0.f, 0.f, 0.f};
#pragma unroll
    for (int nt = 0; nt < 4; ++nt)
#pragma unroll
      for (int p = 0; p < 3; ++p) {
        const short8 bf8 =
            *(const short8*)&Kb[p * 2048 + (nt * 16 + lo) * 32 + quad * 8];
        s4[nt] = __builtin_amdgcn_mfma_f32_16x16x32_bf16(af[p], bf8, s4[nt], 0, 0, 0);
      }

    float alpha[4];
#pragma unroll
    for (int r = 0; r < 4; ++r) {
      const int tq = t0 + w * 16 + quad * 4 + r;
      float sv[4], rm = -1e30f;
#pragma unroll
      for (int nt = 0; nt < 4; ++nt) {
        const int p = kb + nt * 16 + lo;
        const bool ok = (p >= 1) && (p <= tq) && (p + W2 >= tq);
        sv[nt] = ok ? s4[nt][r] * SCALE : -1e30f;
        rm = fmaxf(rm, sv[nt]);
      }
#pragma unroll
      for (int mo = 1; mo < 16; mo <<= 1) rm = fmaxf(rm, __shfl_xor(rm, mo));
      const float m_new = fmaxf(m_run[r], rm);
      float psum = 0.f;
#pragma unroll
      for (int nt = 0; nt < 4; ++nt) {
        const float pv = (sv[nt] > -1e29f) ? __expf(sv[nt] - m_new) : 0.f;
        Pb[w][(nt >> 1) * 512 + (quad * 4 + r) * 32 + (nt & 1) * 16 + lo] = f2bf(pv);
        psum += pv;
      }
#pragma unroll
      for (int mo = 1; mo < 16; mo <<= 1) psum += __shfl_xor(psum, mo);
      alpha[r] = __expf(m_run[r] - m_new);
      l_run[r] = l_run[r] * alpha[r] + psum;
      m_run[r] = m_new;
    }

#pragma unroll
    for (int nt6 = 0; nt6 < 6; ++nt6)
#pragma unroll
      for (int r = 0; r < 4; ++r) O[nt6][r] *= alpha[r];

    short8 pa[2];
#pragma unroll
    for (int kp = 0; kp < 2; ++kp)
      pa[kp] = *(const short8*)&Pb[w][kp * 512 + lo * 32 + quad * 8];
#pragma unroll
    for (int nt6 = 0; nt6 < 6; ++nt6)
#pragma unroll
      for (int kp = 0; kp < 2; ++kp) {
        const short8 vb8 =
            *(const short8*)&Vt[kp * 3072 + (nt6 * 16 + lo) * 32 + quad * 8];
        O[nt6] = __builtin_amdgcn_mfma_f32_16x16x32_bf16(pa[kp], vb8, O[nt6], 0, 0, 0);
      }
    __syncthreads();
  }

  float sg[4];
#pragma unroll
  for (int r = 0; r < 4; ++r) {
    const int row = w * 16 + quad * 4 + r;
    float part = 0.f;
#pragma unroll
    for (int i = 0; i < 6; ++i) {
      const int d = lo * 6 + i;
      part += bf2f(Qb[(d >> 5) * 2048 + row * 32 + (d & 31)]) * Kg0[d];
    }
#pragma unroll
    for (int mo = 1; mo < 16; mo <<= 1) part += __shfl_xor(part, mo);
    sg[r] = part * SCALE;
  }
#pragma unroll
  for (int r = 0; r < 4; ++r) {
    const float m_new = fmaxf(m_run[r], sg[r]);
    const float al = __expf(m_run[r] - m_new);
    const float pg = __expf(sg[r] - m_new);
    const float inv = 1.0f / (l_run[r] * al + pg);
    ushort* dst = obf + (size_t)(t0 + w * 16 + quad * 4 + r) * DMODEL + h * HD;
#pragma unroll
    for (int nt6 = 0; nt6 < 6; ++nt6) {
      const int d = nt6 * 16 + lo;
      dst[d] = f2bf((O[nt6][r] * al + pg * Vg0[d]) * inv);
    }
  }
}

// ---------------------------------------------------------------------------
// Global row, split-k partials: grid (NH, NGB); 256 keys per block.
// ---------------------------------------------------------------------------
__global__ __launch_bounds__(256) void global_attn_part(
    const float* __restrict__ qg0, const float* __restrict__ kg,
    const float* __restrict__ vg, float* __restrict__ gM,
    float* __restrict__ gL, float* __restrict__ gO) {
  const int h = blockIdx.x;
  const int g = blockIdx.y;
  const int kh = h >> 2;
  const int tid = threadIdx.x;
  const int wv = tid >> 6;
  __shared__ float q[HD];
  __shared__ float sp[256];
  __shared__ float red[4];
  __shared__ float od[2][HD];

  if (tid < HD) q[tid] = qg0[h * HD + tid];
  __syncthreads();

  const int key = g * 256 + tid;
  const float* kp = kg + (size_t)key * KVDIM + kh * HD;
  float d = 0.f;
#pragma unroll
  for (int j = 0; j < 24; ++j) {
    const f32x4 kv = *(const f32x4*)(kp + j * 4);
    const f32x4 qv = *(const f32x4*)(&q[j * 4]);
    d += qv[0] * kv[0] + qv[1] * kv[1] + qv[2] * kv[2] + qv[3] * kv[3];
  }
  d *= SCALE;

  float pm = d;
#pragma unroll
  for (int off = 32; off > 0; off >>= 1) pm = fmaxf(pm, __shfl_down(pm, off));
  if ((tid & 63) == 0) red[wv] = pm;
  __syncthreads();
  const float M = fmaxf(fmaxf(red[0], red[1]), fmaxf(red[2], red[3]));
  __syncthreads();
  const float p = __expf(d - M);
  sp[tid] = p;
  float ps = p;
#pragma unroll
  for (int off = 32; off > 0; off >>= 1) ps += __shfl_down(ps, off);
  if ((tid & 63) == 0) red[wv] = ps;
  __syncthreads();
  const float L = red[0] + red[1] + red[2] + red[3];

  if (tid < 192) {
    const int grp = tid >= HD;
    const int dd = tid - grp * HD;
    float acc = 0.f;
    const float* vp = vg + (size_t)(g * 256 + grp * 128) * KVDIM + kh * HD + dd;
#pragma unroll 4
    for (int i = 0; i < 128; ++i)
      acc = fmaf(sp[grp * 128 + i], vp[(size_t)i * KVDIM], acc);
    od[grp][dd] = acc;
  }
  __syncthreads();
  if (tid < HD) gO[((size_t)h * NGB + g) * HD + tid] = od[0][tid] + od[1][tid];
  if (tid == 0) { gM[h * NGB + g] = M; gL[h * NGB + g] = L; }
}

__global__ void global_attn_comb(const float* __restrict__ gM,
                                 const float* __restrict__ gL,
                                 const float* __restrict__ gO,
                                 ushort* __restrict__ obf) {
  const int h = blockIdx.x;
  const int d = threadIdx.x;
  if (d >= HD) return;
  float M = -1e30f;
  for (int g = 0; g < NGB; ++g) M = fmaxf(M, gM[h * NGB + g]);
  float L = 0.f, O = 0.f;
  for (int g = 0; g < NGB; ++g) {
    const float e = __expf(gM[h * NGB + g] - M);
    L += gL[h * NGB + g] * e;
    O += gO[((size_t)h * NGB + g) * HD + d] * e;
  }
  obf[h * HD + d] = f2bf(O / L);
}

// ---------------------------------------------------------------------------
// Launch
// ---------------------------------------------------------------------------
extern "C" void kernel_launch(void* const* d_in, const int* in_sizes, int n_in,
                              void* d_out, int out_size, void* d_ws, size_t ws_size,
                              hipStream_t stream) {
  const float* x     = (const float*)d_in[0];
  const float* cosf  = (const float*)d_in[1];
  const float* sinf  = (const float*)d_in[2];
  const int*   pid   = (const int*)d_in[3];
  const float* W_qs  = (const float*)d_in[4];
  const float* W_ks  = (const float*)d_in[5];
  const float* W_vs  = (const float*)d_in[6];
  const float* W_qg  = (const float*)d_in[7];
  const float* W_kg  = (const float*)d_in[8];
  const float* W_vg  = (const float*)d_in[9];
  const float* W_o   = (const float*)d_in[10];
  float* out = (float*)d_out;

  char* p = (char*)d_ws;
  auto alloc = [&](size_t bytes) { char* r = p; p += (bytes + 255) & ~(size_t)255; return r; };
  float*  kg     = (float*)alloc((size_t)T_LEN * KVDIM * 4);
  float*  vg     = (float*)alloc((size_t)T_LEN * KVDIM * 4);
  float*  qg0    = (float*)alloc(DMODEL * 4);
  ushort* x_bf   = (ushort*)alloc((size_t)T_LEN * DMODEL * 2);
  ushort* q_bf   = (ushort*)alloc((size_t)T_LEN * DMODEL * 2);
  ushort* attnbf = (ushort*)alloc((size_t)T_LEN * DMODEL * 2);
  ushort* k_bf   = (ushort*)alloc((size_t)T_LEN * KVDIM * 2);
  ushort* v_bf   = (ushort*)alloc((size_t)T_LEN * KVDIM * 2);
  ushort* vt_g   = (ushort*)alloc((size_t)KVDIM * T_LEN * 2);
  ushort* Wall   = (ushort*)alloc((size_t)NPROJ * DMODEL * 2);  // q + 4 KV
  ushort* Wo_t   = (ushort*)alloc((size_t)DMODEL * DMODEL * 2);
  float*  gM     = (float*)alloc((size_t)NH * NGB * 4);
  float*  gL     = (float*)alloc((size_t)NH * NGB * 4);
  float*  gO     = (float*)alloc((size_t)NH * NGB * HD * 4);

  const dim3 blk(256);
  const int nX4 = (T_LEN * DMODEL) / 4;

  // bf16 conversions / weight transposes (packed into Wall)
  convert_bf16<<<(nX4 + 255) / 256, blk, 0, stream>>>(x, x_bf, nX4);
  transpose_bf16<<<dim3(DMODEL / 32, DMODEL / 32), blk, 0, stream>>>(W_qs, Wall, DMODEL, DMODEL);
  transpose_bf16<<<dim3(DMODEL / 32, DMODEL / 32), blk, 0, stream>>>(W_o,  Wo_t, DMODEL, DMODEL);
  transpose_bf16_kv4<<<dim3(KVDIM / 32, DMODEL / 32, 4), blk, 0, stream>>>(
      W_ks, W_vs, W_kg, W_vg, Wall + (size_t)DMODEL * DMODEL);

  // Unified projection GEMM (256^2 deep-pipelined) with fused RoPE epilogue
  gemm_proj256<<<dim3(NPROJ / 256, T_LEN / 256), dim3(512), 0, stream>>>(
      x_bf, Wall, q_bf, k_bf, v_bf, kg, vg, cosf, sinf, pid);

  // qg row 0 (RoPE at pos 0 is identity -> skipped)
  qg0_zero<<<DMODEL / 256, blk, 0, stream>>>(qg0);
  qg0_split<<<dim3(DMODEL / 256, DMODEL / 128), blk, 0, stream>>>(x, W_qg, qg0);

  // V pre-transpose for local attention
  transpose_u16<<<dim3(KVDIM / 32, T_LEN / 32), blk, 0, stream>>>(v_bf, vt_g);

  // Attention
  local_attn_v4<<<dim3(T_LEN / 64, NH), blk, 0, stream>>>(
      q_bf, k_bf, vt_g, kg, vg, attnbf);
  global_attn_part<<<dim3(NH, NGB), blk, 0, stream>>>(qg0, kg, vg, gM, gL, gO);
  global_attn_comb<<<NH, dim3(128), 0, stream>>>(gM, gL, gO, attnbf);

  // Output projection (256^2 deep-pipelined)
  gemm_out256<<<dim3(DMODEL / 256, T_LEN / 256), dim3(512), 0, stream>>>(
      attnbf, Wo_t, out);
}